// Round 1
// baseline (801.072 us; speedup 1.0000x reference)
//
#include <hip/hip_runtime.h>
#include <hip/hip_bf16.h>

typedef _Float16 half8 __attribute__((ext_vector_type(8)));
typedef _Float16 half4 __attribute__((ext_vector_type(4)));
typedef float f32x4 __attribute__((ext_vector_type(4)));

#define E_TOTAL 800000
#define EMBD 128
#define KDIM 384
#define BM 64
#define APAD 392                 // halfs per A row (384 + 8 pad -> conflict-light, 16B aligned)
#define WROW 40                  // halfs per W-slab row (32 + 8 pad)
#define SLAB_HALFS (128 * WROW)  // 5120 halfs = 10240 B
#define NSLAB 12

// ---- P: convert W_dense fp32 [128][384] -> f16 slabs in ws: slab s = [n=0..127][kk=0..31] (+8 pad)
__global__ __launch_bounds__(256) void prep_w(const float* __restrict__ Wd,
                                              _Float16* __restrict__ wsW) {
    int id = blockIdx.x * 256 + threadIdx.x;          // < 49152
    int c = id / KDIM;
    int k = id - c * KDIM;
    wsW[(k >> 5) * SLAB_HALFS + c * WROW + (k & 31)] = (_Float16)Wd[id];
}

// ---- A: rbf_env = envelope(x) * sin(n*pi*x)/x
__global__ __launch_bounds__(256) void env_kernel(const float* __restrict__ d,
                                                  float* __restrict__ out1) {
    int e = blockIdx.x * 256 + threadIdx.x;           // grid exact: 800000/256
    float x = d[e] * 0.2f;                            // d / CUTOFF
    float inv = 1.0f / x;
    float x2 = x * x;
    float x5 = x2 * x2 * x;
    // p=6: 1/x - 28 x^5 + 48 x^6 - 21 x^7
    float env = inv + x5 * (-28.0f + x * (48.0f - 21.0f * x));
    float einv = env * inv;
    const float PI = 3.14159265358979323846f;
    float px = PI * x;
    float* o = out1 + e * 6;
    #pragma unroll
    for (int n = 1; n <= 6; n++) {
        o[n - 1] = einv * __sinf(px * (float)n);
    }
}

// ---- B: fused gather + rbf-proj + GEMM(E x 384 @ 384 x 128) + silu
__global__ __launch_bounds__(256) void main_kernel(
    const int* __restrict__ Z, const int* __restrict__ src, const int* __restrict__ dst,
    const float* __restrict__ rbf, const float* __restrict__ emb,
    const float* __restrict__ W_rbf, const float* __restrict__ b_rbf,
    const float* __restrict__ b_dense, const _Float16* __restrict__ wsW,
    float* __restrict__ out0) {
    __shared__ _Float16 Alds[BM * APAD];        // 50176 B
    __shared__ _Float16 Wlds[2 * SLAB_HALFS];   // 20480 B (double buffer)
    __shared__ float s_wrbf[EMBD * 6];
    __shared__ float s_brbf[EMBD];
    __shared__ float s_bd[EMBD];

    const int tid = threadIdx.x;
    const int w = tid >> 6;      // wave 0..3
    const int l = tid & 63;
    const int e0 = blockIdx.x * BM;

    if (tid < EMBD) { s_brbf[tid] = b_rbf[tid]; s_bd[tid] = b_dense[tid]; }
    for (int i = tid; i < EMBD * 6; i += 256) s_wrbf[i] = W_rbf[i];

    // stage W slab 0 into buffer 0
    {
        const float4* sv = (const float4*)(wsW);
        float4* dv = (float4*)(Wlds);
        for (int o = tid; o < 640; o += 256) dv[o] = sv[o];
    }
    __syncthreads();  // s_wrbf/s_brbf visible for the build phase

    // ---- build A tile: [64 edges][384] f16 in LDS. 4 threads per edge.
    {
        int m = tid >> 2, q = tid & 3;
        int e = e0 + m;
        int zs = Z[src[e]];
        int zd = Z[dst[e]];
        const float4* rs = (const float4*)(emb + zs * EMBD) + q * 8;
        const float4* rd = (const float4*)(emb + zd * EMBD) + q * 8;
        _Float16* arow = &Alds[m * APAD];
        #pragma unroll
        for (int i = 0; i < 8; i++) {
            float4 f = rs[i];
            half4 h = {(_Float16)f.x, (_Float16)f.y, (_Float16)f.z, (_Float16)f.w};
            *(half4*)&arow[q * 32 + 4 * i] = h;
        }
        #pragma unroll
        for (int i = 0; i < 8; i++) {
            float4 f = rd[i];
            half4 h = {(_Float16)f.x, (_Float16)f.y, (_Float16)f.z, (_Float16)f.w};
            *(half4*)&arow[EMBD + q * 32 + 4 * i] = h;
        }
        const float* rb = rbf + e * 6;
        float r0 = rb[0], r1 = rb[1], r2 = rb[2], r3 = rb[3], r4 = rb[4], r5 = rb[5];
        for (int c0 = 0; c0 < 32; c0++) {
            int c = q * 32 + c0;
            const float* wr = &s_wrbf[c * 6];
            float pre = s_brbf[c] + r0 * wr[0] + r1 * wr[1] + r2 * wr[2] +
                        r3 * wr[3] + r4 * wr[4] + r5 * wr[5];
            float svl = pre / (1.0f + __expf(-pre));
            arow[2 * EMBD + c] = (_Float16)svl;
        }
    }
    __syncthreads();  // A tile + W slab 0 ready

    f32x4 acc[8];
    #pragma unroll
    for (int i = 0; i < 8; i++) acc[i] = (f32x4){0.f, 0.f, 0.f, 0.f};

    const int lr = l & 15;   // col-in-tile (B/C) / row-in-tile (A)
    const int lg = l >> 4;   // quad group

    #pragma unroll 2
    for (int s = 0; s < NSLAB; s++) {
        // prefetch next slab into the other LDS buffer while computing this one
        if (s < NSLAB - 1) {
            const float4* sv = (const float4*)(wsW + (s + 1) * SLAB_HALFS);
            float4* dv = (float4*)(Wlds + ((s + 1) & 1) * SLAB_HALFS);
            for (int o = tid; o < 640; o += 256) dv[o] = sv[o];
        }
        half8 a = *(const half8*)&Alds[(16 * w + lr) * APAD + 32 * s + lg * 8];
        const _Float16* wb = &Wlds[(s & 1) * SLAB_HALFS + lg * 8];
        #pragma unroll
        for (int nt = 0; nt < 8; nt++) {
            half8 b = *(const half8*)&wb[(nt * 16 + lr) * WROW];
            acc[nt] = __builtin_amdgcn_mfma_f32_16x16x32_f16(a, b, acc[nt], 0, 0, 0);
        }
        __syncthreads();
    }

    // ---- epilogue: bias + silu, fp32 stores
    const int rowbase = e0 + 16 * w + lg * 4;
    #pragma unroll
    for (int nt = 0; nt < 8; nt++) {
        int col = nt * 16 + lr;
        float bd = s_bd[col];
        #pragma unroll
        for (int r = 0; r < 4; r++) {
            float v = acc[nt][r] + bd;
            v = v / (1.0f + __expf(-v));
            out0[(rowbase + r) * EMBD + col] = v;
        }
    }
}

extern "C" void kernel_launch(void* const* d_in, const int* in_sizes, int n_in,
                              void* d_out, int out_size, void* d_ws, size_t ws_size,
                              hipStream_t stream) {
    const int* Z = (const int*)d_in[0];
    const int* src = (const int*)d_in[1];
    const int* dst = (const int*)d_in[2];
    const float* rbf = (const float*)d_in[3];
    const float* dvec = (const float*)d_in[4];
    const float* emb = (const float*)d_in[5];
    const float* W_rbf = (const float*)d_in[6];
    const float* b_rbf = (const float*)d_in[7];
    const float* W_dense = (const float*)d_in[8];
    const float* b_dense = (const float*)d_in[9];

    float* out0 = (float*)d_out;
    float* out1 = out0 + (size_t)E_TOTAL * EMBD;
    _Float16* wsW = (_Float16*)d_ws;  // 12 slabs * 5120 halfs = 122880 B

    prep_w<<<(KDIM * EMBD) / 256, 256, 0, stream>>>(W_dense, wsW);
    env_kernel<<<E_TOTAL / 256, 256, 0, stream>>>(dvec, out1);
    main_kernel<<<E_TOTAL / BM, 256, 0, stream>>>(Z, src, dst, rbf, emb, W_rbf, b_rbf,
                                                  b_dense, wsW, out0);
}